// Round 4
// baseline (20588.490 us; speedup 1.0000x reference)
//
#include <hip/hip_runtime.h>

#define BB 64
#define NN 1000
#define FF 12
#define EE 64
#define HH 128
#define OO 16

__device__ __forceinline__ float rcp_(float x){ return __builtin_amdgcn_rcpf(x); }
// tanh(x) = 1 - 2/(e^{2x}+1)
__device__ __forceinline__ float tanh_(float x){ return 1.0f - 2.0f*rcp_(__expf(2.0f*x) + 1.0f); }

// quad_perm DPP: 0xB1 = [1,0,3,2] (xor1), 0x4E = [2,3,0,1] (xor2), 0xFF = bcast lane3
template<int CTRL>
__device__ __forceinline__ float qswz_(float x){
    int r = __builtin_amdgcn_update_dpp(0, __float_as_int(x), CTRL, 0xF, 0xF, true);
    return __int_as_float(r);
}
// v + row_shifted(v), OOB lanes contribute 0 (bound_ctrl). 0x114=row_shr:4, 0x118=row_shr:8
template<int CTRL>
__device__ __forceinline__ float dppza_(float v){
    int s = __builtin_amdgcn_update_dpp(0, __float_as_int(v), CTRL, 0xF, 0xF, true);
    return v + __int_as_float(s);
}
// cross-half (lanes 0-31 <-> 32-63) sum in all lanes, VALU-only
__device__ __forceinline__ float plx32_(float v){
    float a, b;
    asm volatile("v_mov_b32 %0, %2\n\t"
                 "v_mov_b32 %1, %2\n\t"
                 "v_permlane32_swap_b32 %0, %1"
                 : "=&v"(a), "=&v"(b) : "v"(v));
    return a + b;
}
// barrier draining only LDS counters; global loads/stores stay in flight
__device__ __forceinline__ void barrier_lds_(){
    asm volatile("s_waitcnt lgkmcnt(0)" ::: "memory");
    __builtin_amdgcn_s_barrier();
    asm volatile("" ::: "memory");
}

__global__ __launch_bounds__(512, 2)
void decoder_kernel(const float* __restrict__ enc,   // (B,1,N,E)
                    const float* __restrict__ mean,  // (B,FUT,N,O)
                    const float* __restrict__ sv,    // (1,O)
                    const float* __restrict__ h0,    // (2,O)
                    const float* __restrict__ c0,    // (2,H)
                    const float* __restrict__ Wih0,  // (G, E+O)
                    const float* __restrict__ Whh0,  // (G, O)
                    const float* __restrict__ bih0,  // (G)
                    const float* __restrict__ bhh0,  // (G)
                    const float* __restrict__ Whr0,  // (O, H)
                    const float* __restrict__ Wih1,  // (G, O)
                    const float* __restrict__ Whh1,  // (G, O)
                    const float* __restrict__ bih1,  // (G)
                    const float* __restrict__ bhh1,  // (G)
                    const float* __restrict__ Whr1,  // (O, H)
                    float* __restrict__ out)         // (B,FUT,N,O)
{
    const int t   = threadIdx.x;     // 512 threads
    const int b   = blockIdx.x;
    const int l   = t & 63;          // lane in wave
    const int k   = t >> 2;          // cell 0..127 (quad-owned)
    const int tau = t & 3;           // 0=i 1=f 2=g 3=o
    const int g   = tau*HH + k;      // gate row (both layers)

    __shared__ __align__(16) float s_h1a[2][2][16];  // [pingpong][half][j]
    __shared__ __align__(16) float s_h2a[2][2][16];
    __shared__ __align__(16) float s_nm[2][OO];      // node_mean, slot n&1
    __shared__ __align__(16) float s_enc[EE];        // enc(node)

    // ---- per-thread weights (static-indexed) ----
    float wl0[16], wh0[16], wi1[16], wh1[16], wr0[4], wr1[4];
    {
        const float4* pL = (const float4*)(Wih0 + (size_t)g*(EE+OO) + EE);
        const float4* pH = (const float4*)(Whh0 + (size_t)g*OO);
        const float4* pI = (const float4*)(Wih1 + (size_t)g*OO);
        const float4* pG = (const float4*)(Whh1 + (size_t)g*OO);
        #pragma unroll
        for (int i=0;i<4;i++){
            float4 v;
            v=pL[i]; wl0[4*i]=v.x; wl0[4*i+1]=v.y; wl0[4*i+2]=v.z; wl0[4*i+3]=v.w;
            v=pH[i]; wh0[4*i]=v.x; wh0[4*i+1]=v.y; wh0[4*i+2]=v.z; wh0[4*i+3]=v.w;
            v=pI[i]; wi1[4*i]=v.x; wi1[4*i+1]=v.y; wi1[4*i+2]=v.z; wi1[4*i+3]=v.w;
            v=pG[i]; wh1[4*i]=v.x; wh1[4*i+1]=v.y; wh1[4*i+2]=v.z; wh1[4*i+3]=v.w;
        }
        // proj: this quad's cell contributes to j = 4*tau + u
        #pragma unroll
        for (int u=0;u<4;u++){
            wr0[u] = Whr0[(size_t)(4*tau+u)*HH + k];
            wr1[u] = Whr1[(size_t)(4*tau+u)*HH + k];
        }
    }
    const float bias0r = bih0[g] + bhh0[g];
    const float bias1r = bih1[g] + bhh1[g];
    // step-0 correction: gates1's h2-dot uses sv seed; true h2_0 = h0[1]
    float corr1 = 0.f;
    #pragma unroll
    for (int i=0;i<4;i++){
        float4 hv  = *(const float4*)(h0 + OO + 4*i);
        float4 svv = *(const float4*)(sv + 4*i);
        corr1 += (hv.x-svv.x)*wh1[4*i]   + (hv.y-svv.y)*wh1[4*i+1]
               + (hv.z-svv.z)*wh1[4*i+2] + (hv.w-svv.w)*wh1[4*i+3];
    }
    const float am = (tau==2) ? 2.0f : 1.0f;   // branch-free sigm/tanh selector

    float c1v = c0[k];
    float c2v = c0[HH+k];

    const float* encB  = enc  + (size_t)b * NN * EE;
    const float* meanB = mean + (size_t)b * FF * NN * OO;
    float*       outB  = out  + (size_t)b * FF * NN * OO;

    // ---- prologue ----
    if (t < 32){
        ((float*)s_h1a[0])[t] = 0.f;
        ((float*)s_h1a[1])[t] = 0.f;
        ((float*)s_h2a[1])[t] = 0.f;
        ((float*)s_h2a[0])[t] = (t < OO) ? sv[t] : 0.f;   // 'last' seed
    }
    if (t < OO){
        ((float4*)s_enc)[t] = ((const float4*)encB)[t];   // enc node 0
    } else if (t < 2*OO){
        const int j = t - OO;
        float a = 0.f;
        #pragma unroll
        for (int ff=0; ff<FF; ++ff) a += meanB[((size_t)ff*NN)*OO + j];
        s_nm[0][j] = a * (1.0f/12.0f);
    }
    __syncthreads();

    // aH_pre = Whh0-row . h1(0)  (h0 row 0, broadcast loads)
    float aH_pre;
    {
        float y0=0,y1=0,y2=0,y3=0;
        #pragma unroll
        for (int i=0;i<4;i++){
            y0 += h0[i]   *wh0[i];    y1 += h0[4+i] *wh0[4+i];
            y2 += h0[8+i] *wh0[8+i];  y3 += h0[12+i]*wh0[12+i];
        }
        aH_pre = (y0+y1)+(y2+y3);
    }
    // pre0(node 0) = bias0 + enc.Wrow + nm.wl0
    float pre0;
    {
        float s = bias0r;
        const float4* wp = (const float4*)(Wih0 + (size_t)g*(EE+OO));
        const float4* ep = (const float4*)s_enc;
        #pragma unroll
        for (int e=0;e<16;e++){
            float4 wv = wp[e], ev = ep[e];
            s += ev.x*wv.x + ev.y*wv.y + ev.z*wv.z + ev.w*wv.w;
        }
        const float4* nm4 = (const float4*)s_nm[0];
        #pragma unroll
        for (int i=0;i<4;i++){
            float4 m = nm4[i];
            s += m.x*wl0[4*i] + m.y*wl0[4*i+1] + m.z*wl0[4*i+2] + m.w*wl0[4*i+3];
        }
        pre0 = s;
    }

    float4 ef = make_float4(0.f,0.f,0.f,0.f);
    float nmr[12];
    #pragma unroll
    for (int i=0;i<12;i++) nmr[i]=0.f;
    float aH2_pre = 0.f;

    int step = 0;
    #pragma unroll 1
    for (int n = 0; n < NN; ++n){
        #pragma unroll 1
        for (int f = 0; f < FF; ++f, ++step){
            const int rp = step & 1;

            // ================= PHASE A : layer 0 =================
            float h2v[16];
            {
                const float4* ga = (const float4*)&s_h2a[rp][0][0];
                const float4* gb = (const float4*)&s_h2a[rp][1][0];
                #pragma unroll
                for (int i=0;i<4;i++){
                    float4 a = ga[i], c = gb[i];
                    h2v[4*i]=a.x+c.x; h2v[4*i+1]=a.y+c.y; h2v[4*i+2]=a.z+c.z; h2v[4*i+3]=a.w+c.w;
                }
            }
            // deferred output write for step t-1 (reads old s_nm slot)
            if (step > 0 && t < OO){
                const int fp = (f==0) ? (FF-1) : (f-1);
                const int np = (f==0) ? (n-1)  : n;
                const int sl = (f==0) ? ((n&1)^1) : (n&1);
                outB[((size_t)fp*NN + np)*OO + t] = s_h2a[rp][0][t] + s_h2a[rp][1][t] + s_nm[sl][t];
            }
            if (t < 32) ((float*)s_h2a[rp^1])[t] = 0.f;   // zero phase-B target

            // gates0: on-chain dot = wl0 . h2 (tree); h1-dot precomputed (aH_pre)
            float aL;
            {
                float x0=0,x1=0,x2=0,x3=0;
                #pragma unroll
                for (int i=0;i<4;i++){
                    x0 += h2v[i]   *wl0[i];    x1 += h2v[4+i] *wl0[4+i];
                    x2 += h2v[8+i] *wl0[8+i];  x3 += h2v[12+i]*wl0[12+i];
                }
                aL = (x0+x1)+(x2+x3);
            }
            float xg  = pre0 + aL + aH_pre;
            float act = 1.f - am * rcp_(__expf(am*xg) + 1.f);   // sigm or tanh

            // cell0: quad DPP dance (lane tau: 0=i 1=f 2=g 3=o)
            float r2 = qswz_<0x4E>(act);
            float P  = act * r2;
            float s2 = (tau==1) ? act*c1v : P;
            float cn = s2 + qswz_<0xB1>(s2);
            c1v = cn;
            float tc = tanh_(cn);
            float hf = act * qswz_<0x4E>(tc);      // valid in lane tau==3

            // proj0: quad-bcast + per-lane 4-j contribs, in-register reduce, 2-group atomics
            {
                float hb = qswz_<0xFF>(hf);
                float p0 = hb*wr0[0], p1 = hb*wr0[1], p2 = hb*wr0[2], p3 = hb*wr0[3];
                p0 = dppza_<0x114>(p0); p1 = dppza_<0x114>(p1); p2 = dppza_<0x114>(p2); p3 = dppza_<0x114>(p3);
                p0 = dppza_<0x118>(p0); p1 = dppza_<0x118>(p1); p2 = dppza_<0x118>(p2); p3 = dppza_<0x118>(p3);
                p0 = plx32_(p0); p1 = plx32_(p1); p2 = plx32_(p2); p3 = plx32_(p3);
                if (l < 32 && (l & 12) == 12){      // lanes 12-15 (half0), 28-31 (half1)
                    float* dst = &s_h1a[rp^1][l>>4][4*tau];
                    atomicAdd(dst+0, p0); atomicAdd(dst+1, p1);
                    atomicAdd(dst+2, p2); atomicAdd(dst+3, p3);
                }
            }

            // precompute phase-B's h2-dot (off-chain)
            {
                float y0=0,y1=0,y2=0,y3=0;
                #pragma unroll
                for (int i=0;i<4;i++){
                    y0 += h2v[i]   *wh1[i];    y1 += h2v[4+i] *wh1[4+i];
                    y2 += h2v[8+i] *wh1[8+i];  y3 += h2v[12+i]*wh1[12+i];
                }
                aH2_pre = (y0+y1)+(y2+y3);
            }
            barrier_lds_();                          // B1

            // ================= PHASE B : layer 1 =================
            float h1n[16];
            {
                const float4* ga = (const float4*)&s_h1a[rp^1][0][0];
                const float4* gb = (const float4*)&s_h1a[rp^1][1][0];
                #pragma unroll
                for (int i=0;i<4;i++){
                    float4 a = ga[i], c = gb[i];
                    h1n[4*i]=a.x+c.x; h1n[4*i+1]=a.y+c.y; h1n[4*i+2]=a.z+c.z; h1n[4*i+3]=a.w+c.w;
                }
            }
            if (t < 32) ((float*)s_h1a[rp])[t] = 0.f;   // zero next phase-A target

            // prefetch node n+1 (issue f==8, land f==10)
            if (f == 8 && n+1 < NN){
                if (t < OO){
                    ef = ((const float4*)(encB + (size_t)(n+1)*EE))[t];
                } else if (t < 2*OO){
                    const int j = t - OO;
                    #pragma unroll
                    for (int ff=0; ff<FF; ++ff) nmr[ff] = meanB[((size_t)ff*NN + (n+1))*OO + j];
                }
            }
            if (f == 10 && n+1 < NN){
                if (t < OO){
                    ((float4*)s_enc)[t] = ef;
                } else if (t < 2*OO){
                    float a = 0.f;
                    #pragma unroll
                    for (int ff=0; ff<FF; ++ff) a += nmr[ff];
                    s_nm[(n+1)&1][t-OO] = a * (1.0f/12.0f);
                }
            }

            // gates1: on-chain dot = wi1 . h1 (tree); h2-dot precomputed
            float aI;
            {
                float x0=0,x1=0,x2=0,x3=0;
                #pragma unroll
                for (int i=0;i<4;i++){
                    x0 += h1n[i]   *wi1[i];    x1 += h1n[4+i] *wi1[4+i];
                    x2 += h1n[8+i] *wi1[8+i];  x3 += h1n[12+i]*wi1[12+i];
                }
                aI = (x0+x1)+(x2+x3);
            }
            float xg1 = bias1r + aI + aH2_pre;
            if (step == 0) xg1 += corr1;
            float act1 = 1.f - am * rcp_(__expf(am*xg1) + 1.f);

            // cell1
            float r2b = qswz_<0x4E>(act1);
            float Pb  = act1 * r2b;
            float s2b = (tau==1) ? act1*c2v : Pb;
            float cnb = s2b + qswz_<0xB1>(s2b);
            c2v = cnb;
            float tcb = tanh_(cnb);
            float hf2 = act1 * qswz_<0x4E>(tcb);

            // proj1
            {
                float hb = qswz_<0xFF>(hf2);
                float p0 = hb*wr1[0], p1 = hb*wr1[1], p2 = hb*wr1[2], p3 = hb*wr1[3];
                p0 = dppza_<0x114>(p0); p1 = dppza_<0x114>(p1); p2 = dppza_<0x114>(p2); p3 = dppza_<0x114>(p3);
                p0 = dppza_<0x118>(p0); p1 = dppza_<0x118>(p1); p2 = dppza_<0x118>(p2); p3 = dppza_<0x118>(p3);
                p0 = plx32_(p0); p1 = plx32_(p1); p2 = plx32_(p2); p3 = plx32_(p3);
                if (l < 32 && (l & 12) == 12){
                    float* dst = &s_h2a[rp^1][l>>4][4*tau];
                    atomicAdd(dst+0, p0); atomicAdd(dst+1, p1);
                    atomicAdd(dst+2, p2); atomicAdd(dst+3, p3);
                }
            }

            // precompute next phase-A's h1-dot (off-chain)
            {
                float y0=0,y1=0,y2=0,y3=0;
                #pragma unroll
                for (int i=0;i<4;i++){
                    y0 += h1n[i]   *wh0[i];    y1 += h1n[4+i] *wh0[4+i];
                    y2 += h1n[8+i] *wh0[8+i];  y3 += h1n[12+i]*wh0[12+i];
                }
                aH_pre = (y0+y1)+(y2+y3);
            }

            // recompute pre0 for node n+1 in the f==11 bubble (enc/nm landed at f==10)
            if (f == 11 && n+1 < NN){
                float s = bias0r;
                const float4* wp = (const float4*)(Wih0 + (size_t)g*(EE+OO));
                const float4* ep = (const float4*)s_enc;
                #pragma unroll
                for (int e=0;e<16;e++){
                    float4 wv = wp[e], ev = ep[e];
                    s += ev.x*wv.x + ev.y*wv.y + ev.z*wv.z + ev.w*wv.w;
                }
                const float4* nm4 = (const float4*)s_nm[(n+1)&1];
                #pragma unroll
                for (int i=0;i<4;i++){
                    float4 m = nm4[i];
                    s += m.x*wl0[4*i] + m.y*wl0[4*i+1] + m.z*wl0[4*i+2] + m.w*wl0[4*i+3];
                }
                pre0 = s;
            }
            barrier_lds_();                          // B2
        }
    }

    // epilogue: final step (n=NN-1, f=FF-1) landed in s_h2a[0]
    if (t < OO)
        outB[((size_t)(FF-1)*NN + (NN-1))*OO + t] =
            s_h2a[0][0][t] + s_h2a[0][1][t] + s_nm[(NN-1)&1][t];
}

extern "C" void kernel_launch(void* const* d_in, const int* in_sizes, int n_in,
                              void* d_out, int out_size, void* d_ws, size_t ws_size,
                              hipStream_t stream) {
    const float* enc  = (const float*)d_in[0];
    const float* mean = (const float*)d_in[1];
    const float* sv   = (const float*)d_in[2];
    const float* h0   = (const float*)d_in[3];
    const float* c0   = (const float*)d_in[4];
    const float* Wih0 = (const float*)d_in[5];
    const float* Whh0 = (const float*)d_in[6];
    const float* bih0 = (const float*)d_in[7];
    const float* bhh0 = (const float*)d_in[8];
    const float* Whr0 = (const float*)d_in[9];
    const float* Wih1 = (const float*)d_in[10];
    const float* Whh1 = (const float*)d_in[11];
    const float* bih1 = (const float*)d_in[12];
    const float* bhh1 = (const float*)d_in[13];
    const float* Whr1 = (const float*)d_in[14];
    float* out = (float*)d_out;

    decoder_kernel<<<dim3(BB), dim3(512), 0, stream>>>(
        enc, mean, sv, h0, c0,
        Wih0, Whh0, bih0, bhh0, Whr0,
        Wih1, Whh1, bih1, bhh1, Whr1,
        out);
}

// Round 5
// 18096.724 us; speedup vs baseline: 1.1377x; 1.1377x over previous
//
#include <hip/hip_runtime.h>

#define BB 64
#define NN 1000
#define FF 12
#define EE 64
#define HH 128
#define OO 16

__device__ __forceinline__ float rcp_(float x){ return __builtin_amdgcn_rcpf(x); }
// tanh(x) = 1 - 2/(e^{2x}+1)
__device__ __forceinline__ float tanh_(float x){ return 1.0f - 2.0f*rcp_(__expf(2.0f*x) + 1.0f); }

// quad_perm DPP: 0xB1 = [1,0,3,2] (xor1), 0x4E = [2,3,0,1] (xor2)
template<int CTRL>
__device__ __forceinline__ float qswz_(float x){
    int r = __builtin_amdgcn_update_dpp(0, __float_as_int(x), CTRL, 0xF, 0xF, true);
    return __int_as_float(r);
}
// barrier draining only LDS counters; global loads/stores stay in flight
__device__ __forceinline__ void barrier_lds_(){
    asm volatile("s_waitcnt lgkmcnt(0)" ::: "memory");
    __builtin_amdgcn_s_barrier();
    asm volatile("" ::: "memory");
}

__global__ __launch_bounds__(512, 2)
void decoder_kernel(const float* __restrict__ enc,   // (B,1,N,E)
                    const float* __restrict__ mean,  // (B,FUT,N,O)
                    const float* __restrict__ sv,    // (1,O)
                    const float* __restrict__ h0,    // (2,O)
                    const float* __restrict__ c0,    // (2,H)
                    const float* __restrict__ Wih0,  // (G, E+O)
                    const float* __restrict__ Whh0,  // (G, O)
                    const float* __restrict__ bih0,  // (G)
                    const float* __restrict__ bhh0,  // (G)
                    const float* __restrict__ Whr0,  // (O, H)
                    const float* __restrict__ Wih1,  // (G, O)
                    const float* __restrict__ Whh1,  // (G, O)
                    const float* __restrict__ bih1,  // (G)
                    const float* __restrict__ bhh1,  // (G)
                    const float* __restrict__ Whr1,  // (O, H)
                    float* __restrict__ out)         // (B,FUT,N,O)
{
    const int t   = threadIdx.x;     // 512 threads
    const int b   = blockIdx.x;
    const int k   = t >> 2;          // cell 0..127 (gate mapping)
    const int tau = t & 3;           // 0=i 1=f 2=g 3=o
    const int g   = tau*HH + k;      // gate row (both layers)
    const int j16 = t >> 5;          // proj mapping: output j (16 groups of 32)
    const int ln  = t & 31;          // lane within proj group
    const int kb  = ln * 4;          // proj k-chunk base

    __shared__ __align__(16) float s_h1[OO];
    __shared__ __align__(16) float s_h2[OO];
    __shared__ __align__(16) float s_hf[HH];
    __shared__ __align__(16) float s_enc[EE];
    __shared__ __align__(16) float s_nm[2][OO];

    // ---- per-thread weights (static-indexed) ----
    float wl0[16], wh0[16], wi1[16], wh1[16], wp0[4], wp1[4];
    {
        const float4* pL = (const float4*)(Wih0 + (size_t)g*(EE+OO) + EE);
        const float4* pH = (const float4*)(Whh0 + (size_t)g*OO);
        const float4* pI = (const float4*)(Wih1 + (size_t)g*OO);
        const float4* pG = (const float4*)(Whh1 + (size_t)g*OO);
        #pragma unroll
        for (int i=0;i<4;i++){
            float4 v;
            v=pL[i]; wl0[4*i]=v.x; wl0[4*i+1]=v.y; wl0[4*i+2]=v.z; wl0[4*i+3]=v.w;
            v=pH[i]; wh0[4*i]=v.x; wh0[4*i+1]=v.y; wh0[4*i+2]=v.z; wh0[4*i+3]=v.w;
            v=pI[i]; wi1[4*i]=v.x; wi1[4*i+1]=v.y; wi1[4*i+2]=v.z; wi1[4*i+3]=v.w;
            v=pG[i]; wh1[4*i]=v.x; wh1[4*i+1]=v.y; wh1[4*i+2]=v.z; wh1[4*i+3]=v.w;
        }
        float4 q0 = *(const float4*)(Whr0 + (size_t)j16*HH + kb);
        float4 q1 = *(const float4*)(Whr1 + (size_t)j16*HH + kb);
        wp0[0]=q0.x; wp0[1]=q0.y; wp0[2]=q0.z; wp0[3]=q0.w;
        wp1[0]=q1.x; wp1[1]=q1.y; wp1[2]=q1.z; wp1[3]=q1.w;
    }
    const float bias0r = bih0[g] + bhh0[g];
    const float bias1r = bih1[g] + bhh1[g];
    // step-0 correction: P1's aH2_pre uses s_h2 seeded with sv; true h2_0 = h0[1]
    float corr1 = 0.f;
    #pragma unroll
    for (int i=0;i<4;i++){
        float4 hv  = *(const float4*)(h0 + OO + 4*i);
        float4 svv = *(const float4*)(sv + 4*i);
        corr1 += (hv.x-svv.x)*wh1[4*i]   + (hv.y-svv.y)*wh1[4*i+1]
               + (hv.z-svv.z)*wh1[4*i+2] + (hv.w-svv.w)*wh1[4*i+3];
    }
    const float am = (tau==2) ? 2.0f : 1.0f;   // branch-free sigm/tanh selector

    float c1v = c0[k];
    float c2v = c0[HH+k];

    const float* encB  = enc  + (size_t)b * NN * EE;
    const float* meanB = mean + (size_t)b * FF * NN * OO;
    float*       outB  = out  + (size_t)b * FF * NN * OO;

    // ---- prologue ----
    if (t < OO){
        s_h1[t] = h0[t];
        s_h2[t] = sv[t];                                  // 'last' seed
        ((float4*)s_enc)[t] = ((const float4*)encB)[t];   // enc node 0
    } else if (t < 2*OO){
        const int j = t - OO;
        float a = 0.f;
        #pragma unroll
        for (int ff=0; ff<FF; ++ff) a += meanB[((size_t)ff*NN)*OO + j];
        s_nm[0][j] = a * (1.0f/12.0f);
    }
    __syncthreads();

    // aH_pre = wh0-row . h1(0)   (h0 row 0, broadcast global loads)
    float aH_pre;
    {
        float y0=0,y1=0,y2=0,y3=0;
        #pragma unroll
        for (int i=0;i<4;i++){
            y0 += h0[i]   *wh0[i];    y1 += h0[4+i] *wh0[4+i];
            y2 += h0[8+i] *wh0[8+i];  y3 += h0[12+i]*wh0[12+i];
        }
        aH_pre = (y0+y1)+(y2+y3);
    }
    // pre0(node 0) = bias0 + enc.Wrow + nm.wl0
    float pre0;
    {
        float s = bias0r;
        const float4* wp = (const float4*)(Wih0 + (size_t)g*(EE+OO));
        const float4* ep = (const float4*)s_enc;
        #pragma unroll
        for (int e=0;e<16;e++){
            float4 wv = wp[e], ev = ep[e];
            s += ev.x*wv.x + ev.y*wv.y + ev.z*wv.z + ev.w*wv.w;
        }
        const float4* nm4 = (const float4*)s_nm[0];
        #pragma unroll
        for (int i=0;i<4;i++){
            float4 m = nm4[i];
            s += m.x*wl0[4*i] + m.y*wl0[4*i+1] + m.z*wl0[4*i+2] + m.w*wl0[4*i+3];
        }
        pre0 = s;
    }

    float4 ef = make_float4(0.f,0.f,0.f,0.f);
    float nmr[12];
    #pragma unroll
    for (int i=0;i<12;i++) nmr[i]=0.f;
    float aH2_pre = 0.f;

    for (int n = 0; n < NN; ++n){
        for (int f = 0; f < FF; ++f){
            // ============ P1 : layer-0 gates + cell (quad dance) ============
            float h2v[16];
            {
                const float4* pa = (const float4*)s_h2;
                #pragma unroll
                for (int i=0;i<4;i++){
                    float4 a = pa[i];
                    h2v[4*i]=a.x; h2v[4*i+1]=a.y; h2v[4*i+2]=a.z; h2v[4*i+3]=a.w;
                }
            }
            float aL;
            {
                float x0=0,x1=0,x2=0,x3=0;
                #pragma unroll
                for (int i=0;i<4;i++){
                    x0 += h2v[i]   *wl0[i];    x1 += h2v[4+i] *wl0[4+i];
                    x2 += h2v[8+i] *wl0[8+i];  x3 += h2v[12+i]*wl0[12+i];
                }
                aL = (x0+x1)+(x2+x3);
            }
            float xg  = pre0 + aL + aH_pre;
            float act = 1.f - am * rcp_(__expf(am*xg) + 1.f);   // sigm or tanh

            float r2 = qswz_<0x4E>(act);
            float P  = act * r2;
            float s2 = (tau==1) ? act*c1v : P;
            float cn = s2 + qswz_<0xB1>(s2);
            c1v = cn;
            float tc = tanh_(cn);
            float hf = act * qswz_<0x4E>(tc);      // valid in lane tau==3
            if (tau == 3) s_hf[k] = hf;

            // off-chain: layer-1's h2-dot for this step
            {
                float y0=0,y1=0,y2=0,y3=0;
                #pragma unroll
                for (int i=0;i<4;i++){
                    y0 += h2v[i]   *wh1[i];    y1 += h2v[4+i] *wh1[4+i];
                    y2 += h2v[8+i] *wh1[8+i];  y3 += h2v[12+i]*wh1[12+i];
                }
                aH2_pre = (y0+y1)+(y2+y3);
            }
            barrier_lds_();                          // B1

            // ============ P2 : projection 0 (baseline pattern) ============
            {
                float4 h4 = *(const float4*)&s_hf[kb];
                float p = h4.x*wp0[0] + h4.y*wp0[1] + h4.z*wp0[2] + h4.w*wp0[3];
                p += __shfl_down(p, 16, 32);
                p += __shfl_down(p,  8, 32);
                p += __shfl_down(p,  4, 32);
                p += __shfl_down(p,  2, 32);
                p += __shfl_down(p,  1, 32);
                if (ln == 0) s_h1[j16] = p;
            }
            barrier_lds_();                          // B2

            // ============ P3 : layer-1 gates + cell ============
            float aI;
            {
                const float4* pa = (const float4*)s_h1;
                float h1v[16];
                #pragma unroll
                for (int i=0;i<4;i++){
                    float4 a = pa[i];
                    h1v[4*i]=a.x; h1v[4*i+1]=a.y; h1v[4*i+2]=a.z; h1v[4*i+3]=a.w;
                }
                float x0=0,x1=0,x2=0,x3=0;
                #pragma unroll
                for (int i=0;i<4;i++){
                    x0 += h1v[i]   *wi1[i];    x1 += h1v[4+i] *wi1[4+i];
                    x2 += h1v[8+i] *wi1[8+i];  x3 += h1v[12+i]*wi1[12+i];
                }
                aI = (x0+x1)+(x2+x3);
            }
            float xg1 = bias1r + aI + aH2_pre;
            if (n == 0 && f == 0) xg1 += corr1;
            float act1 = 1.f - am * rcp_(__expf(am*xg1) + 1.f);

            float r2b = qswz_<0x4E>(act1);
            float Pb  = act1 * r2b;
            float s2b = (tau==1) ? act1*c2v : Pb;
            float cnb = s2b + qswz_<0xB1>(s2b);
            c2v = cnb;
            float tcb = tanh_(cnb);
            float hf2 = act1 * qswz_<0x4E>(tcb);
            if (tau == 3) s_hf[k] = hf2;

            // prefetch node n+1 (issue f==8, land f==10; barriers don't drain vmcnt)
            if (f == 8 && n+1 < NN){
                if (t < OO){
                    ef = ((const float4*)(encB + (size_t)(n+1)*EE))[t];
                } else if (t < 2*OO){
                    const int j = t - OO;
                    #pragma unroll
                    for (int ff=0; ff<FF; ++ff) nmr[ff] = meanB[((size_t)ff*NN + (n+1))*OO + j];
                }
            }
            if (f == 10 && n+1 < NN){
                if (t < OO){
                    ((float4*)s_enc)[t] = ef;
                } else if (t < 2*OO){
                    float a = 0.f;
                    #pragma unroll
                    for (int ff=0; ff<FF; ++ff) a += nmr[ff];
                    s_nm[(n+1)&1][t-OO] = a * (1.0f/12.0f);
                }
            }
            barrier_lds_();                          // B3

            // ============ P4 : projection 1 + output ============
            {
                float4 h4 = *(const float4*)&s_hf[kb];
                float p = h4.x*wp1[0] + h4.y*wp1[1] + h4.z*wp1[2] + h4.w*wp1[3];
                p += __shfl_down(p, 16, 32);
                p += __shfl_down(p,  8, 32);
                p += __shfl_down(p,  4, 32);
                p += __shfl_down(p,  2, 32);
                p += __shfl_down(p,  1, 32);
                if (ln == 0){
                    s_h2[j16] = p;
                    outB[((size_t)f*NN + n)*OO + j16] = p + s_nm[n&1][j16];
                }
            }
            // off-chain: next step's h1-dot (s_h1 unchanged until next P2)
            {
                const float4* pa = (const float4*)s_h1;
                float h1v[16];
                #pragma unroll
                for (int i=0;i<4;i++){
                    float4 a = pa[i];
                    h1v[4*i]=a.x; h1v[4*i+1]=a.y; h1v[4*i+2]=a.z; h1v[4*i+3]=a.w;
                }
                float y0=0,y1=0,y2=0,y3=0;
                #pragma unroll
                for (int i=0;i<4;i++){
                    y0 += h1v[i]   *wh0[i];    y1 += h1v[4+i] *wh0[4+i];
                    y2 += h1v[8+i] *wh0[8+i];  y3 += h1v[12+i]*wh0[12+i];
                }
                aH_pre = (y0+y1)+(y2+y3);
            }
            // recompute pre0 for node n+1 (enc/nm landed at f==10)
            if (f == 11 && n+1 < NN){
                float s = bias0r;
                const float4* wp = (const float4*)(Wih0 + (size_t)g*(EE+OO));
                const float4* ep = (const float4*)s_enc;
                #pragma unroll
                for (int e=0;e<16;e++){
                    float4 wv = wp[e], ev = ep[e];
                    s += ev.x*wv.x + ev.y*wv.y + ev.z*wv.z + ev.w*wv.w;
                }
                const float4* nm4 = (const float4*)s_nm[(n+1)&1];
                #pragma unroll
                for (int i=0;i<4;i++){
                    float4 m = nm4[i];
                    s += m.x*wl0[4*i] + m.y*wl0[4*i+1] + m.z*wl0[4*i+2] + m.w*wl0[4*i+3];
                }
                pre0 = s;
            }
            barrier_lds_();                          // B4
        }
    }
}

extern "C" void kernel_launch(void* const* d_in, const int* in_sizes, int n_in,
                              void* d_out, int out_size, void* d_ws, size_t ws_size,
                              hipStream_t stream) {
    const float* enc  = (const float*)d_in[0];
    const float* mean = (const float*)d_in[1];
    const float* sv   = (const float*)d_in[2];
    const float* h0   = (const float*)d_in[3];
    const float* c0   = (const float*)d_in[4];
    const float* Wih0 = (const float*)d_in[5];
    const float* Whh0 = (const float*)d_in[6];
    const float* bih0 = (const float*)d_in[7];
    const float* bhh0 = (const float*)d_in[8];
    const float* Whr0 = (const float*)d_in[9];
    const float* Wih1 = (const float*)d_in[10];
    const float* Whh1 = (const float*)d_in[11];
    const float* bih1 = (const float*)d_in[12];
    const float* bhh1 = (const float*)d_in[13];
    const float* Whr1 = (const float*)d_in[14];
    float* out = (float*)d_out;

    decoder_kernel<<<dim3(BB), dim3(512), 0, stream>>>(
        enc, mean, sv, h0, c0,
        Wih0, Whh0, bih0, bhh0, Whr0,
        Wih1, Whh1, bih1, bhh1, Whr1,
        out);
}

// Round 6
// 18006.581 us; speedup vs baseline: 1.1434x; 1.0050x over previous
//
#include <hip/hip_runtime.h>

#define BB 64
#define NN 1000
#define FF 12
#define EE 64
#define HH 128
#define OO 16

__device__ __forceinline__ float rcp_(float x){ return __builtin_amdgcn_rcpf(x); }
// tanh(x) = 1 - 2/(e^{2x}+1)
__device__ __forceinline__ float tanh_(float x){ return 1.0f - 2.0f*rcp_(__expf(2.0f*x) + 1.0f); }

// quad_perm DPP: 0xB1 = [1,0,3,2] (xor1), 0x4E = [2,3,0,1] (xor2)
template<int CTRL>
__device__ __forceinline__ float qswz_(float x){
    int r = __builtin_amdgcn_update_dpp(0, __float_as_int(x), CTRL, 0xF, 0xF, true);
    return __int_as_float(r);
}
// barrier draining only LDS counters; global loads/stores stay in flight
__device__ __forceinline__ void barrier_lds_(){
    asm volatile("s_waitcnt lgkmcnt(0)" ::: "memory");
    __builtin_amdgcn_s_barrier();
    asm volatile("" ::: "memory");
}

__global__ __launch_bounds__(512, 1)
void decoder_kernel(const float* __restrict__ enc,   // (B,1,N,E)
                    const float* __restrict__ mean,  // (B,FUT,N,O)
                    const float* __restrict__ sv,    // (1,O)
                    const float* __restrict__ h0,    // (2,O)
                    const float* __restrict__ c0,    // (2,H)
                    const float* __restrict__ Wih0,  // (G, E+O)
                    const float* __restrict__ Whh0,  // (G, O)
                    const float* __restrict__ bih0,  // (G)
                    const float* __restrict__ bhh0,  // (G)
                    const float* __restrict__ Whr0,  // (O, H)
                    const float* __restrict__ Wih1,  // (G, O)
                    const float* __restrict__ Whh1,  // (G, O)
                    const float* __restrict__ bih1,  // (G)
                    const float* __restrict__ bhh1,  // (G)
                    const float* __restrict__ Whr1,  // (O, H)
                    float* __restrict__ out)         // (B,FUT,N,O)
{
    const int t   = threadIdx.x;     // 512 threads
    const int b   = blockIdx.x;
    const int k   = t >> 2;          // cell 0..127 (gate mapping)
    const int tau = t & 3;           // 0=i 1=f 2=g 3=o
    const int g   = tau*HH + k;      // gate row (both layers)
    const int j16 = t >> 5;          // proj mapping: output j (16 groups of 32)
    const int ln  = t & 31;          // lane within proj group
    const int kb  = ln * 4;          // proj k-chunk base

    __shared__ __align__(16) float s_h1[OO];
    __shared__ __align__(16) float s_h2[OO];
    __shared__ __align__(16) float s_hf[HH];
    __shared__ __align__(16) float s_enc[EE];
    __shared__ __align__(16) float s_nm[2][OO];

    // ---- per-thread weights (static-indexed) ----
    float wl0[16], wh0[16], wi1[16], wh1[16], wp0[4], wp1[4];
    {
        const float4* pL = (const float4*)(Wih0 + (size_t)g*(EE+OO) + EE);
        const float4* pH = (const float4*)(Whh0 + (size_t)g*OO);
        const float4* pI = (const float4*)(Wih1 + (size_t)g*OO);
        const float4* pG = (const float4*)(Whh1 + (size_t)g*OO);
        #pragma unroll
        for (int i=0;i<4;i++){
            float4 v;
            v=pL[i]; wl0[4*i]=v.x; wl0[4*i+1]=v.y; wl0[4*i+2]=v.z; wl0[4*i+3]=v.w;
            v=pH[i]; wh0[4*i]=v.x; wh0[4*i+1]=v.y; wh0[4*i+2]=v.z; wh0[4*i+3]=v.w;
            v=pI[i]; wi1[4*i]=v.x; wi1[4*i+1]=v.y; wi1[4*i+2]=v.z; wi1[4*i+3]=v.w;
            v=pG[i]; wh1[4*i]=v.x; wh1[4*i+1]=v.y; wh1[4*i+2]=v.z; wh1[4*i+3]=v.w;
        }
        float4 q0 = *(const float4*)(Whr0 + (size_t)j16*HH + kb);
        float4 q1 = *(const float4*)(Whr1 + (size_t)j16*HH + kb);
        wp0[0]=q0.x; wp0[1]=q0.y; wp0[2]=q0.z; wp0[3]=q0.w;
        wp1[0]=q1.x; wp1[1]=q1.y; wp1[2]=q1.z; wp1[3]=q1.w;
    }
    const float bias0r = bih0[g] + bhh0[g];
    const float bias1r = bih1[g] + bhh1[g];
    // step-0 correction: gates1's h2-dot reads s_h2 seeded with sv; true h2_0 = h0[1]
    float corr1 = 0.f;
    #pragma unroll
    for (int i=0;i<4;i++){
        float4 hv  = *(const float4*)(h0 + OO + 4*i);
        float4 svv = *(const float4*)(sv + 4*i);
        corr1 += (hv.x-svv.x)*wh1[4*i]   + (hv.y-svv.y)*wh1[4*i+1]
               + (hv.z-svv.z)*wh1[4*i+2] + (hv.w-svv.w)*wh1[4*i+3];
    }
    const float am = (tau==2) ? 2.0f : 1.0f;   // branch-free sigm/tanh selector

    float c1v = c0[k];
    float c2v = c0[HH+k];

    const float* encB  = enc  + (size_t)b * NN * EE;
    const float* meanB = mean + (size_t)b * FF * NN * OO;
    float*       outB  = out  + (size_t)b * FF * NN * OO;

    // ---- prologue ----
    if (t < OO){
        s_h1[t] = h0[t];
        s_h2[t] = sv[t];                                  // 'last' seed
        ((float4*)s_enc)[t] = ((const float4*)encB)[t];   // enc node 0
    } else if (t < 2*OO){
        const int j = t - OO;
        float a = 0.f;
        #pragma unroll
        for (int ff=0; ff<FF; ++ff) a += meanB[((size_t)ff*NN)*OO + j];
        s_nm[0][j] = a * (1.0f/12.0f);
    }
    __syncthreads();

    // pre0(node 0) = bias0 + enc.Wrow + nm.wl0
    float pre0;
    {
        float s = bias0r;
        const float4* wp = (const float4*)(Wih0 + (size_t)g*(EE+OO));
        const float4* ep = (const float4*)s_enc;
        #pragma unroll
        for (int e=0;e<16;e++){
            float4 wv = wp[e], ev = ep[e];
            s += ev.x*wv.x + ev.y*wv.y + ev.z*wv.z + ev.w*wv.w;
        }
        const float4* nm4 = (const float4*)s_nm[0];
        #pragma unroll
        for (int i=0;i<4;i++){
            float4 m = nm4[i];
            s += m.x*wl0[4*i] + m.y*wl0[4*i+1] + m.z*wl0[4*i+2] + m.w*wl0[4*i+3];
        }
        pre0 = s;
    }

    float4 ef = make_float4(0.f,0.f,0.f,0.f);
    float nmr[12];
    #pragma unroll
    for (int i=0;i<12;i++) nmr[i]=0.f;

    for (int n = 0; n < NN; ++n){
        for (int f = 0; f < FF; ++f){
            // ============ P1 : layer-0 gates + cell (quad dance) ============
            float h2v[16];
            float aL, aH;
            {
                const float4* pa = (const float4*)s_h2;
                const float4* pb = (const float4*)s_h1;
                float x0=0,x1=0,x2=0,x3=0, y0=0,y1=0,y2=0,y3=0;
                #pragma unroll
                for (int i=0;i<4;i++){
                    float4 a = pa[i];
                    h2v[4*i]=a.x; h2v[4*i+1]=a.y; h2v[4*i+2]=a.z; h2v[4*i+3]=a.w;
                    x0 += a.x*wl0[4*i]; x1 += a.y*wl0[4*i+1];
                    x2 += a.z*wl0[4*i+2]; x3 += a.w*wl0[4*i+3];
                    float4 c = pb[i];
                    y0 += c.x*wh0[4*i]; y1 += c.y*wh0[4*i+1];
                    y2 += c.z*wh0[4*i+2]; y3 += c.w*wh0[4*i+3];
                }
                aL = (x0+x1)+(x2+x3);
                aH = (y0+y1)+(y2+y3);
            }
            float xg  = pre0 + aL + aH;
            float act = 1.f - am * rcp_(__expf(am*xg) + 1.f);   // sigm or tanh

            float r2 = qswz_<0x4E>(act);
            float P  = act * r2;
            float s2 = (tau==1) ? act*c1v : P;
            float cn = s2 + qswz_<0xB1>(s2);
            c1v = cn;
            float tc = tanh_(cn);
            float hf = act * qswz_<0x4E>(tc);      // valid in lane tau==3
            if (tau == 3) s_hf[k] = hf;
            barrier_lds_();                          // B1

            // ============ P2 : projection 0 ============
            {
                float4 h4 = *(const float4*)&s_hf[kb];
                float p = h4.x*wp0[0] + h4.y*wp0[1] + h4.z*wp0[2] + h4.w*wp0[3];
                p += __shfl_down(p, 16, 32);
                p += __shfl_down(p,  8, 32);
                p += __shfl_down(p,  4, 32);
                p += __shfl_down(p,  2, 32);
                p += __shfl_down(p,  1, 32);
                if (ln == 0) s_h1[j16] = p;
            }
            barrier_lds_();                          // B2

            // ============ P3 : layer-1 gates + cell ============
            float aI, aH2;
            {
                const float4* pa = (const float4*)s_h1;
                float x0=0,x1=0,x2=0,x3=0, y0=0,y1=0,y2=0,y3=0;
                #pragma unroll
                for (int i=0;i<4;i++){
                    float4 a = pa[i];
                    x0 += a.x*wi1[4*i];   x1 += a.y*wi1[4*i+1];
                    x2 += a.z*wi1[4*i+2]; x3 += a.w*wi1[4*i+3];
                    // h2_{t-1} still in registers from P1
                    y0 += h2v[4*i]  *wh1[4*i];   y1 += h2v[4*i+1]*wh1[4*i+1];
                    y2 += h2v[4*i+2]*wh1[4*i+2]; y3 += h2v[4*i+3]*wh1[4*i+3];
                }
                aI  = (x0+x1)+(x2+x3);
                aH2 = (y0+y1)+(y2+y3);
            }
            float xg1 = bias1r + aI + aH2;
            if (n == 0 && f == 0) xg1 += corr1;
            float act1 = 1.f - am * rcp_(__expf(am*xg1) + 1.f);

            float r2b = qswz_<0x4E>(act1);
            float Pb  = act1 * r2b;
            float s2b = (tau==1) ? act1*c2v : Pb;
            float cnb = s2b + qswz_<0xB1>(s2b);
            c2v = cnb;
            float tcb = tanh_(cnb);
            float hf2 = act1 * qswz_<0x4E>(tcb);
            if (tau == 3) s_hf[k] = hf2;

            // prefetch node n+1 (issue f==8, land f==10; barriers don't drain vmcnt)
            if (f == 8 && n+1 < NN){
                if (t < OO){
                    ef = ((const float4*)(encB + (size_t)(n+1)*EE))[t];
                } else if (t < 2*OO){
                    const int j = t - OO;
                    #pragma unroll
                    for (int ff=0; ff<FF; ++ff) nmr[ff] = meanB[((size_t)ff*NN + (n+1))*OO + j];
                }
            }
            if (f == 10 && n+1 < NN){
                if (t < OO){
                    ((float4*)s_enc)[t] = ef;
                } else if (t < 2*OO){
                    float a = 0.f;
                    #pragma unroll
                    for (int ff=0; ff<FF; ++ff) a += nmr[ff];
                    s_nm[(n+1)&1][t-OO] = a * (1.0f/12.0f);
                }
            }
            barrier_lds_();                          // B3

            // ============ P4 : projection 1 + output ============
            {
                float4 h4 = *(const float4*)&s_hf[kb];
                float p = h4.x*wp1[0] + h4.y*wp1[1] + h4.z*wp1[2] + h4.w*wp1[3];
                p += __shfl_down(p, 16, 32);
                p += __shfl_down(p,  8, 32);
                p += __shfl_down(p,  4, 32);
                p += __shfl_down(p,  2, 32);
                p += __shfl_down(p,  1, 32);
                if (ln == 0){
                    s_h2[j16] = p;
                    outB[((size_t)f*NN + n)*OO + j16] = p + s_nm[n&1][j16];
                }
            }
            // recompute pre0 for node n+1 (enc/nm landed at f==10; 1/12 of steps)
            if (f == 11 && n+1 < NN){
                float s = bias0r;
                const float4* wp = (const float4*)(Wih0 + (size_t)g*(EE+OO));
                const float4* ep = (const float4*)s_enc;
                #pragma unroll
                for (int e=0;e<16;e++){
                    float4 wv = wp[e], ev = ep[e];
                    s += ev.x*wv.x + ev.y*wv.y + ev.z*wv.z + ev.w*wv.w;
                }
                const float4* nm4 = (const float4*)s_nm[(n+1)&1];
                #pragma unroll
                for (int i=0;i<4;i++){
                    float4 m = nm4[i];
                    s += m.x*wl0[4*i] + m.y*wl0[4*i+1] + m.z*wl0[4*i+2] + m.w*wl0[4*i+3];
                }
                pre0 = s;
            }
            barrier_lds_();                          // B4
        }
    }
}

extern "C" void kernel_launch(void* const* d_in, const int* in_sizes, int n_in,
                              void* d_out, int out_size, void* d_ws, size_t ws_size,
                              hipStream_t stream) {
    const float* enc  = (const float*)d_in[0];
    const float* mean = (const float*)d_in[1];
    const float* sv   = (const float*)d_in[2];
    const float* h0   = (const float*)d_in[3];
    const float* c0   = (const float*)d_in[4];
    const float* Wih0 = (const float*)d_in[5];
    const float* Whh0 = (const float*)d_in[6];
    const float* bih0 = (const float*)d_in[7];
    const float* bhh0 = (const float*)d_in[8];
    const float* Whr0 = (const float*)d_in[9];
    const float* Wih1 = (const float*)d_in[10];
    const float* Whh1 = (const float*)d_in[11];
    const float* bih1 = (const float*)d_in[12];
    const float* bhh1 = (const float*)d_in[13];
    const float* Whr1 = (const float*)d_in[14];
    float* out = (float*)d_out;

    decoder_kernel<<<dim3(BB), dim3(512), 0, stream>>>(
        enc, mean, sv, h0, c0,
        Wih0, Whh0, bih0, bhh0, Whr0,
        Wih1, Whh1, bih1, bhh1, Whr1,
        out);
}